// Round 4
// baseline (10400.852 us; speedup 1.0000x reference)
//
#include <hip/hip_runtime.h>

#define NN 100000
#define NE 3200000

typedef unsigned int u32;

__device__ __forceinline__ int clampi(int s){
  s = s < 0 ? 0 : s;
  return s >= NN ? NN-1 : s;
}

template<int N4>
__device__ __forceinline__ float dotl(const float* __restrict__ a, const float* w){
  float acc = 0.f;
  #pragma unroll
  for (int k = 0; k < N4; ++k){
    float4 q = ((const float4*)w)[k];
    acc += a[4*k]*q.x + a[4*k+1]*q.y + a[4*k+2]*q.z + a[4*k+3]*q.w;
  }
  return acc;
}

// ---------------- K1: h1 = x @ c1_Wx^T ; hs1 = h1.a_src ; hd1 = h1.a_dst ----
__global__ __launch_bounds__(256,4) void k1(const float* __restrict__ x,
    const float* __restrict__ Wx, const float* __restrict__ asrc, const float* __restrict__ adst,
    float* __restrict__ h1, float* __restrict__ hs1, float* __restrict__ hd1)
{
  __shared__ float wL[64], aS[16], aD[16];
  int tid = threadIdx.x;
  if (tid < 64) wL[tid] = Wx[tid];
  if (tid < 16){ aS[tid] = asrc[tid]; aD[tid] = adst[tid]; }
  __syncthreads();
  int n = blockIdx.x*256 + tid;
  if (n >= NN) return;
  float4 xr = ((const float4*)x)[n];
  float hs=0.f, hd=0.f;
  float* hrow = h1 + (size_t)n*16;
  #pragma unroll
  for (int j=0;j<16;j++){
    float h = xr.x*wL[j*4+0] + xr.y*wL[j*4+1] + xr.z*wL[j*4+2] + xr.w*wL[j*4+3];
    hrow[j] = h; hs += h*aS[j]; hd += h*aD[j];
  }
  hs1[n]=hs; hd1[n]=hd;
}

// ---------------- K2: conv1 edge phase (unnormalized accumulate) ------------
__global__ __launch_bounds__(256,4) void k2(const int* __restrict__ ei,
    const float* __restrict__ ea, const float* __restrict__ We, const float* __restrict__ aedge,
    const float* __restrict__ h1, const float* __restrict__ hs1, const float* __restrict__ hd1,
    float* __restrict__ s1, float* __restrict__ x1a)
{
  __shared__ float w6[6];
  int tid = threadIdx.x;
  if (tid < 6){
    float acc = 0.f;
    for (int j=0;j<16;j++) acc += aedge[j] * We[j*6+tid];
    w6[tid] = acc;
  }
  __syncthreads();
  int i = blockIdx.x*256 + tid;
  if (i >= NE) return;
  int s = clampi(ei[i]);
  int d = clampi(ei[NE + i]);
  const float2* eap = (const float2*)ea + (size_t)i*3;
  float2 u0 = eap[0], u1 = eap[1], u2 = eap[2];
  float alpha = hs1[s] + hd1[d]
    + u0.x*w6[0] + u0.y*w6[1] + u1.x*w6[2]
    + u1.y*w6[3] + u2.x*w6[4] + u2.y*w6[5];
  alpha = alpha > 0.f ? alpha : 0.2f*alpha;
  float ex = __expf(alpha);
  unsafeAtomicAdd(&s1[d], ex);
  const float4* hp = (const float4*)(h1 + (size_t)s*16);
  float4 h0=hp[0], h1v=hp[1], h2v=hp[2], h3v=hp[3];
  float* xa = x1a + (size_t)d*16;
  unsafeAtomicAdd(xa+0,  ex*h0.x);  unsafeAtomicAdd(xa+1,  ex*h0.y);
  unsafeAtomicAdd(xa+2,  ex*h0.z);  unsafeAtomicAdd(xa+3,  ex*h0.w);
  unsafeAtomicAdd(xa+4,  ex*h1v.x); unsafeAtomicAdd(xa+5,  ex*h1v.y);
  unsafeAtomicAdd(xa+6,  ex*h1v.z); unsafeAtomicAdd(xa+7,  ex*h1v.w);
  unsafeAtomicAdd(xa+8,  ex*h2v.x); unsafeAtomicAdd(xa+9,  ex*h2v.y);
  unsafeAtomicAdd(xa+10, ex*h2v.z); unsafeAtomicAdd(xa+11, ex*h2v.w);
  unsafeAtomicAdd(xa+12, ex*h3v.x); unsafeAtomicAdd(xa+13, ex*h3v.y);
  unsafeAtomicAdd(xa+14, ex*h3v.z); unsafeAtomicAdd(xa+15, ex*h3v.w);
}

// ---------------- K4: x1 = x1a/s1 + b1 ; h2 = x1 @ c2_Wx^T ; hs2 ; hd2 ------
__global__ __launch_bounds__(256,4) void k4(const float* __restrict__ x1a,
    const float* __restrict__ s1, const float* __restrict__ c1b, const float* __restrict__ Wx2,
    const float* __restrict__ a2s, const float* __restrict__ a2d,
    float* __restrict__ x1, float* __restrict__ h2,
    float* __restrict__ hs2, float* __restrict__ hd2)
{
  __shared__ float wL[256], bL[16], aS[16], aD[16];
  int tid = threadIdx.x;
  wL[tid] = Wx2[tid];
  if (tid < 16){ bL[tid]=c1b[tid]; aS[tid]=a2s[tid]; aD[tid]=a2d[tid]; }
  __syncthreads();
  int n = blockIdx.x*256 + tid;
  if (n >= NN) return;
  float inv = 1.f/(s1[n] + 1e-16f);
  float v[16];
  const float* xp = x1a + (size_t)n*16;
  float* x1r = x1 + (size_t)n*16;
  #pragma unroll
  for (int j=0;j<16;j++){ v[j] = xp[j]*inv + bL[j]; x1r[j] = v[j]; }
  float hs=0.f, hd=0.f;
  float* h2r = h2 + (size_t)n*16;
  #pragma unroll
  for (int j=0;j<16;j++){
    float acc = 0.f;
    #pragma unroll
    for (int k=0;k<16;k++) acc += v[k]*wL[j*16+k];
    h2r[j] = acc; hs += acc*aS[j]; hd += acc*aD[j];
  }
  hs2[n]=hs; hd2[n]=hd;
}

// ---------------- K5: edge MLP + edge head + conv2 edge phase ---------------
__global__ __launch_bounds__(256,2) void k5(
    const int* __restrict__ ei, const float* __restrict__ ea,
    const float* __restrict__ x1, const float* __restrict__ h2,
    const float* __restrict__ hs2, const float* __restrict__ hd2,
    const float* w1p, const float* b1p, const float* w2p, const float* b2p,
    const float* w3p, const float* b3p, const float* w4p, const float* b4p,
    const float* We2, const float* a2e,
    const float* ew1p, const float* eb1p, const float* ew2p, const float* eb2p,
    float* __restrict__ s2, float* __restrict__ x2a, float* __restrict__ eout)
{
  __shared__ __align__(16) float w1L[32*40]; __shared__ float b1L[32];
  __shared__ __align__(16) float w2L[64*32]; __shared__ float b2L[64];
  __shared__ __align__(16) float w3L[32*64]; __shared__ float b3L[32];
  __shared__ __align__(16) float w4L[16*32]; __shared__ float b4L[16];
  __shared__ __align__(16) float ew1L[16*16]; __shared__ float eb1L[16];
  __shared__ __align__(16) float ew2L[4*16];  __shared__ float eb2L[4];
  __shared__ float w16L[16];
  int tid = threadIdx.x;
  for (int idx=tid; idx<32*40; idx+=256){ int j=idx/40, k=idx-j*40; w1L[idx] = (k<38) ? w1p[j*38+k] : 0.f; }
  for (int idx=tid; idx<64*32; idx+=256) w2L[idx] = w2p[idx];
  for (int idx=tid; idx<32*64; idx+=256) w3L[idx] = w3p[idx];
  for (int idx=tid; idx<16*32; idx+=256) w4L[idx] = w4p[idx];
  ew1L[tid] = ew1p[tid];
  if (tid < 64){ ew2L[tid] = ew2p[tid]; b2L[tid] = b2p[tid]; }
  if (tid < 32){ b1L[tid] = b1p[tid]; b3L[tid] = b3p[tid]; }
  if (tid < 16){
    b4L[tid]=b4p[tid]; eb1L[tid]=eb1p[tid];
    float acc=0.f;
    for (int j=0;j<16;j++) acc += a2e[j] * We2[j*16+tid];
    w16L[tid]=acc;
  }
  if (tid < 4) eb2L[tid] = eb2p[tid];
  __syncthreads();

  for (int i = blockIdx.x*256 + tid; i < NE; i += gridDim.x*256){
    int s = clampi(ei[i]);
    int d = clampi(ei[NE + i]);
    float f[40];
    {
      const float4* xs = (const float4*)(x1 + (size_t)s*16);
      float4 q0=xs[0], q1=xs[1], q2=xs[2], q3=xs[3];
      f[0]=q0.x; f[1]=q0.y; f[2]=q0.z; f[3]=q0.w;
      f[4]=q1.x; f[5]=q1.y; f[6]=q1.z; f[7]=q1.w;
      f[8]=q2.x; f[9]=q2.y; f[10]=q2.z; f[11]=q2.w;
      f[12]=q3.x; f[13]=q3.y; f[14]=q3.z; f[15]=q3.w;
      const float2* eap = (const float2*)ea + (size_t)i*3;
      float2 u0=eap[0], u1=eap[1], u2=eap[2];
      f[16]=u0.x; f[17]=u0.y; f[18]=u1.x;
      f[19]=u1.y; f[20]=u2.x; f[21]=u2.y;
      const float4* xd = (const float4*)(x1 + (size_t)d*16);
      float4 r0=xd[0], r1=xd[1], r2=xd[2], r3=xd[3];
      f[22]=r0.x; f[23]=r0.y; f[24]=r0.z; f[25]=r0.w;
      f[26]=r1.x; f[27]=r1.y; f[28]=r1.z; f[29]=r1.w;
      f[30]=r2.x; f[31]=r2.y; f[32]=r2.z; f[33]=r2.w;
      f[34]=r3.x; f[35]=r3.y; f[36]=r3.z; f[37]=r3.w;
      f[38]=0.f; f[39]=0.f;
    }
    float a1[32];
    #pragma unroll
    for (int j=0;j<32;j++) a1[j] = fmaxf(dotl<10>(f, &w1L[j*40]) + b1L[j], 0.f);
    float a2[64];
    #pragma unroll
    for (int j=0;j<64;j++) a2[j] = fmaxf(dotl<8>(a1, &w2L[j*32]) + b2L[j], 0.f);
    float a3[32];
    #pragma unroll
    for (int j=0;j<32;j++) a3[j] = fmaxf(dotl<16>(a2, &w3L[j*64]) + b3L[j], 0.f);
    float e[16];
    #pragma unroll
    for (int j=0;j<16;j++) e[j] = dotl<8>(a3, &w4L[j*32]) + b4L[j];

    // edge head + log_softmax (4)
    float t[16];
    #pragma unroll
    for (int j=0;j<16;j++) t[j] = fmaxf(dotl<4>(e, &ew1L[j*16]) + eb1L[j], 0.f);
    float y0 = fmaxf(dotl<4>(t, &ew2L[0])  + eb2L[0], 0.f);
    float y1 = fmaxf(dotl<4>(t, &ew2L[16]) + eb2L[1], 0.f);
    float y2 = fmaxf(dotl<4>(t, &ew2L[32]) + eb2L[2], 0.f);
    float y3 = fmaxf(dotl<4>(t, &ew2L[48]) + eb2L[3], 0.f);
    float m = fmaxf(fmaxf(y0,y1), fmaxf(y2,y3));
    float l = m + __logf(__expf(y0-m)+__expf(y1-m)+__expf(y2-m)+__expf(y3-m));
    float4 eo; eo.x = y0-l; eo.y = y1-l; eo.z = y2-l; eo.w = y3-l;
    ((float4*)eout)[i] = eo;

    // conv2 edge phase
    float al = hs2[s] + hd2[d];
    #pragma unroll
    for (int k=0;k<16;k++) al += e[k]*w16L[k];
    al = al > 0.f ? al : 0.2f*al;
    float ex = __expf(al);
    unsafeAtomicAdd(&s2[d], ex);
    const float4* hp = (const float4*)(h2 + (size_t)s*16);
    float4 h0=hp[0], h1v=hp[1], h2v=hp[2], h3v=hp[3];
    float* xa = x2a + (size_t)d*16;
    unsafeAtomicAdd(xa+0,  ex*h0.x);  unsafeAtomicAdd(xa+1,  ex*h0.y);
    unsafeAtomicAdd(xa+2,  ex*h0.z);  unsafeAtomicAdd(xa+3,  ex*h0.w);
    unsafeAtomicAdd(xa+4,  ex*h1v.x); unsafeAtomicAdd(xa+5,  ex*h1v.y);
    unsafeAtomicAdd(xa+6,  ex*h1v.z); unsafeAtomicAdd(xa+7,  ex*h1v.w);
    unsafeAtomicAdd(xa+8,  ex*h2v.x); unsafeAtomicAdd(xa+9,  ex*h2v.y);
    unsafeAtomicAdd(xa+10, ex*h2v.z); unsafeAtomicAdd(xa+11, ex*h2v.w);
    unsafeAtomicAdd(xa+12, ex*h3v.x); unsafeAtomicAdd(xa+13, ex*h3v.y);
    unsafeAtomicAdd(xa+14, ex*h3v.z); unsafeAtomicAdd(xa+15, ex*h3v.w);
  }
}

// ---------------- K7: x2 -> node head -> log_softmax(2) --------------------
__global__ __launch_bounds__(256,4) void k7(const float* __restrict__ x2a,
    const float* __restrict__ s2, const float* __restrict__ c2b,
    const float* __restrict__ w1p, const float* __restrict__ b1p,
    const float* __restrict__ w2p, const float* __restrict__ b2p,
    float* __restrict__ nout)
{
  __shared__ float wL[256], bL[16], w2L[32], b2L[2], cb[16];
  int tid = threadIdx.x;
  wL[tid] = w1p[tid];
  if (tid < 16){ bL[tid]=b1p[tid]; cb[tid]=c2b[tid]; }
  if (tid < 32) w2L[tid] = w2p[tid];
  if (tid < 2)  b2L[tid] = b2p[tid];
  __syncthreads();
  int n = blockIdx.x*256 + tid;
  if (n >= NN) return;
  float inv = 1.f/(s2[n] + 1e-16f);
  const float* xp = x2a + (size_t)n*16;
  float v[16];
  #pragma unroll
  for (int j=0;j<16;j++) v[j] = xp[j]*inv + cb[j];
  float t[16];
  #pragma unroll
  for (int j=0;j<16;j++){
    float acc = bL[j];
    #pragma unroll
    for (int k=0;k<16;k++) acc += v[k]*wL[j*16+k];
    t[j] = fmaxf(acc, 0.f);
  }
  float y0 = b2L[0], y1 = b2L[1];
  #pragma unroll
  for (int k=0;k<16;k++){ y0 += t[k]*w2L[k]; y1 += t[k]*w2L[16+k]; }
  y0 = fmaxf(y0, 0.f); y1 = fmaxf(y1, 0.f);
  float m = fmaxf(y0, y1);
  float l = m + __logf(__expf(y0-m) + __expf(y1-m));
  float2 no; no.x = y0-l; no.y = y1-l;
  ((float2*)nout)[n] = no;
}

extern "C" void kernel_launch(void* const* d_in, const int* in_sizes, int n_in,
                              void* d_out, int out_size, void* d_ws, size_t ws_size,
                              hipStream_t stream)
{
  const float* x  = (const float*)d_in[0];
  const int* ei   = (const int*)d_in[1];
  const float* ea = (const float*)d_in[2];
  const float* c1Wx = (const float*)d_in[3];
  const float* c1We = (const float*)d_in[4];
  const float* c1as = (const float*)d_in[5];
  const float* c1ad = (const float*)d_in[6];
  const float* c1ae = (const float*)d_in[7];
  const float* c1b  = (const float*)d_in[8];
  const float* e1w1 = (const float*)d_in[9];
  const float* e1b1 = (const float*)d_in[10];
  const float* e1w2 = (const float*)d_in[11];
  const float* e1b2 = (const float*)d_in[12];
  const float* e1w3 = (const float*)d_in[13];
  const float* e1b3 = (const float*)d_in[14];
  const float* e1w4 = (const float*)d_in[15];
  const float* e1b4 = (const float*)d_in[16];
  const float* c2Wx = (const float*)d_in[17];
  const float* c2We = (const float*)d_in[18];
  const float* c2as = (const float*)d_in[19];
  const float* c2ad = (const float*)d_in[20];
  const float* c2ae = (const float*)d_in[21];
  const float* c2b  = (const float*)d_in[22];
  const float* nlw1 = (const float*)d_in[23];
  const float* nlb1 = (const float*)d_in[24];
  const float* nlw2 = (const float*)d_in[25];
  const float* nlb2 = (const float*)d_in[26];
  const float* elw1 = (const float*)d_in[27];
  const float* elb1 = (const float*)d_in[28];
  const float* elw2 = (const float*)d_in[29];
  const float* elb2 = (const float*)d_in[30];

  float* ws = (float*)d_ws;
  const size_t N = NN;
  float* h1  = ws;
  float* hs1 = ws + 16*N;
  float* hd1 = ws + 17*N;
  float* x1  = ws + 18*N;
  float* h2  = ws + 34*N;
  float* hs2 = ws + 50*N;
  float* hd2 = ws + 51*N;
  float* s1  = ws + 52*N;   // zeroed region starts here
  float* x1a = ws + 53*N;
  float* s2  = ws + 69*N;
  float* x2a = ws + 70*N;   // zeroed region ends at 86*N

  hipMemsetAsync(s1, 0, 34*N*sizeof(float), stream);

  float* nout = (float*)d_out;             // [100000, 2] f32
  float* eout = (float*)d_out + 200000;    // [3200000, 4] f32

  k1<<<(NN+255)/256, 256, 0, stream>>>(x, c1Wx, c1as, c1ad, h1, hs1, hd1);
  k2<<<(NE+255)/256, 256, 0, stream>>>(ei, ea, c1We, c1ae, h1, hs1, hd1, s1, x1a);
  k4<<<(NN+255)/256, 256, 0, stream>>>(x1a, s1, c1b, c2Wx, c2as, c2ad, x1, h2, hs2, hd2);
  k5<<<2048, 256, 0, stream>>>(ei, ea, x1, h2, hs2, hd2,
      e1w1, e1b1, e1w2, e1b2, e1w3, e1b3, e1w4, e1b4,
      c2We, c2ae, elw1, elb1, elw2, elb2,
      s2, x2a, eout);
  k7<<<(NN+255)/256, 256, 0, stream>>>(x2a, s2, c2b, nlw1, nlb1, nlw2, nlb2, nout);
}

// Round 5
// 1588.554 us; speedup vs baseline: 6.5474x; 6.5474x over previous
//
#include <hip/hip_runtime.h>

#define NN 100000
#define NE 3200000

typedef unsigned int u32;

__device__ __forceinline__ int clampi(int s){
  s = s < 0 ? 0 : s;
  return s >= NN ? NN-1 : s;
}

template<int N4>
__device__ __forceinline__ float dotl(const float* __restrict__ a, const float* w){
  float acc = 0.f;
  #pragma unroll
  for (int k = 0; k < N4; ++k){
    float4 q = ((const float4*)w)[k];
    acc += a[4*k]*q.x + a[4*k+1]*q.y + a[4*k+2]*q.z + a[4*k+3]*q.w;
  }
  return acc;
}

// ---------------- khist: cnt[d]++ ------------------------------------------
__global__ __launch_bounds__(256,8) void khist(const int* __restrict__ ei, int* __restrict__ cnt){
  int i = blockIdx.x*256 + threadIdx.x;
  if (i >= NE) return;
  atomicAdd(&cnt[clampi(ei[NE+i])], 1);
}

// ---------------- kscan: off = exclusive_scan(cnt); cnt = 0 ----------------
__global__ void kscan(int* __restrict__ cnt, int* __restrict__ off){
  __shared__ int wsum[16];
  __shared__ int carry;
  int tid = threadIdx.x;
  if (tid == 0) carry = 0;
  __syncthreads();
  for (int base = 0; base < NN; base += 1024){
    int i = base + tid;
    int v = (i < NN) ? cnt[i] : 0;
    int x = v;
    #pragma unroll
    for (int ofs = 1; ofs < 64; ofs <<= 1){
      int t = __shfl_up(x, ofs, 64);
      if ((tid & 63) >= ofs) x += t;
    }
    if ((tid & 63) == 63) wsum[tid >> 6] = x;
    __syncthreads();
    if (tid < 16){
      int y = wsum[tid];
      #pragma unroll
      for (int ofs = 1; ofs < 16; ofs <<= 1){
        int t = __shfl_up(y, ofs, 64);
        if (tid >= ofs) y += t;
      }
      wsum[tid] = y;
    }
    __syncthreads();
    int wb = (tid >= 64) ? wsum[(tid >> 6) - 1] : 0;
    int incl = wb + x;
    if (i < NN){ off[i] = carry + incl - v; cnt[i] = 0; }
    int ctot = wsum[15];
    __syncthreads();
    if (tid == 0) carry += ctot;
    __syncthreads();
  }
  if (tid == 0) off[NN] = carry;
}

// ---------------- k1: h1 = x @ c1_Wx^T ; hs1 ; hd1 --------------------------
__global__ __launch_bounds__(256,4) void k1(const float* __restrict__ x,
    const float* __restrict__ Wx, const float* __restrict__ asrc, const float* __restrict__ adst,
    float* __restrict__ h1, float* __restrict__ hs1, float* __restrict__ hd1)
{
  __shared__ float wL[64], aS[16], aD[16];
  int tid = threadIdx.x;
  if (tid < 64) wL[tid] = Wx[tid];
  if (tid < 16){ aS[tid] = asrc[tid]; aD[tid] = adst[tid]; }
  __syncthreads();
  int n = blockIdx.x*256 + tid;
  if (n >= NN) return;
  float4 xr = ((const float4*)x)[n];
  float hs=0.f, hd=0.f;
  float* hrow = h1 + (size_t)n*16;
  #pragma unroll
  for (int j=0;j<16;j++){
    float h = xr.x*wL[j*4+0] + xr.y*wL[j*4+1] + xr.z*wL[j*4+2] + xr.w*wL[j*4+3];
    hrow[j] = h; hs += h*aS[j]; hd += h*aD[j];
  }
  hs1[n]=hs; hd1[n]=hd;
}

// ---------------- k2a: alpha1 -> scatter (ex, src) into CSR slot ------------
__global__ __launch_bounds__(256,8) void k2a(const int* __restrict__ ei,
    const float* __restrict__ ea, const float* __restrict__ We, const float* __restrict__ aedge,
    const float* __restrict__ hs1, const float* __restrict__ hd1,
    const int* __restrict__ off, int* __restrict__ cnt, float2* __restrict__ edata)
{
  __shared__ float w6[6];
  int tid = threadIdx.x;
  if (tid < 6){
    float acc = 0.f;
    for (int j=0;j<16;j++) acc += aedge[j] * We[j*6+tid];
    w6[tid] = acc;
  }
  __syncthreads();
  int i = blockIdx.x*256 + tid;
  if (i >= NE) return;
  int s = clampi(ei[i]);
  int d = clampi(ei[NE + i]);
  const float2* eap = (const float2*)ea + (size_t)i*3;
  float2 u0 = eap[0], u1 = eap[1], u2 = eap[2];
  float al = hs1[s] + hd1[d]
    + u0.x*w6[0] + u0.y*w6[1] + u1.x*w6[2]
    + u1.y*w6[3] + u2.x*w6[4] + u2.y*w6[5];
  al = al > 0.f ? al : 0.2f*al;
  float ex = __expf(al);
  int pos = off[d] + atomicAdd(&cnt[d], 1);
  edata[pos] = make_float2(ex, __int_as_float(s));
}

// ---------------- kagg: per-node CSR reduce (16 lanes = 16 features) --------
__global__ __launch_bounds__(256,4) void kagg(const float2* __restrict__ edata,
    const int* __restrict__ off, const float* __restrict__ h,
    float* __restrict__ acc, float* __restrict__ s, int* __restrict__ cnt)
{
  int n = (blockIdx.x*256 + threadIdx.x) >> 4;
  int j = threadIdx.x & 15;
  if (n >= NN) return;
  int beg = off[n], end = off[n+1];
  float aj = 0.f, sl = 0.f;
  for (int k = beg; k < end; ++k){
    float2 p = edata[k];
    int src = __float_as_int(p.y);
    aj += p.x * h[(size_t)src*16 + j];
    sl += p.x;
  }
  acc[(size_t)n*16 + j] = aj;
  if (j == 0){ s[n] = sl; cnt[n] = 0; }
}

// ---------------- k4: x1 = acc/s + b1 ; h2 = x1 @ c2_Wx^T ; hs2 ; hd2 -------
__global__ __launch_bounds__(256,4) void k4(const float* __restrict__ accb,
    const float* __restrict__ sb, const float* __restrict__ c1b, const float* __restrict__ Wx2,
    const float* __restrict__ a2s, const float* __restrict__ a2d,
    float* __restrict__ x1, float* __restrict__ h2,
    float* __restrict__ hs2, float* __restrict__ hd2)
{
  __shared__ float wL[256], bL[16], aS[16], aD[16];
  int tid = threadIdx.x;
  wL[tid] = Wx2[tid];
  if (tid < 16){ bL[tid]=c1b[tid]; aS[tid]=a2s[tid]; aD[tid]=a2d[tid]; }
  __syncthreads();
  int n = blockIdx.x*256 + tid;
  if (n >= NN) return;
  float inv = 1.f/(sb[n] + 1e-16f);
  float v[16];
  const float* xp = accb + (size_t)n*16;
  float* x1r = x1 + (size_t)n*16;
  #pragma unroll
  for (int j=0;j<16;j++){ v[j] = xp[j]*inv + bL[j]; x1r[j] = v[j]; }
  float hs=0.f, hd=0.f;
  float* h2r = h2 + (size_t)n*16;
  #pragma unroll
  for (int j=0;j<16;j++){
    float acc = 0.f;
    #pragma unroll
    for (int k=0;k<16;k++) acc += v[k]*wL[j*16+k];
    h2r[j] = acc; hs += acc*aS[j]; hd += acc*aD[j];
  }
  hs2[n]=hs; hd2[n]=hd;
}

// ---------------- k5: edge MLP + edge head + alpha2 scatter -----------------
__global__ __launch_bounds__(256,4) void k5(
    const int* __restrict__ ei, const float* __restrict__ ea,
    const float* __restrict__ x1,
    const float* __restrict__ hs2, const float* __restrict__ hd2,
    const float* w1p, const float* b1p, const float* w2p, const float* b2p,
    const float* w3p, const float* b3p, const float* w4p, const float* b4p,
    const float* We2, const float* a2e,
    const float* ew1p, const float* eb1p, const float* ew2p, const float* eb2p,
    const int* __restrict__ off, int* __restrict__ cnt, float2* __restrict__ edata,
    float* __restrict__ eout)
{
  __shared__ __align__(16) float w1L[32*40]; __shared__ float b1L[32];
  __shared__ __align__(16) float w2L[64*32]; __shared__ float b2L[64];
  __shared__ __align__(16) float w3L[32*64]; __shared__ float b3L[32];
  __shared__ __align__(16) float w4L[16*32]; __shared__ float b4L[16];
  __shared__ __align__(16) float ew1L[16*16]; __shared__ float eb1L[16];
  __shared__ __align__(16) float ew2L[4*16];  __shared__ float eb2L[4];
  __shared__ float w16L[16];
  int tid = threadIdx.x;
  for (int idx=tid; idx<32*40; idx+=256){ int j=idx/40, k=idx-j*40; w1L[idx] = (k<38) ? w1p[j*38+k] : 0.f; }
  for (int idx=tid; idx<64*32; idx+=256) w2L[idx] = w2p[idx];
  for (int idx=tid; idx<32*64; idx+=256) w3L[idx] = w3p[idx];
  for (int idx=tid; idx<16*32; idx+=256) w4L[idx] = w4p[idx];
  ew1L[tid] = ew1p[tid];
  if (tid < 64){ ew2L[tid] = ew2p[tid]; b2L[tid] = b2p[tid]; }
  if (tid < 32){ b1L[tid] = b1p[tid]; b3L[tid] = b3p[tid]; }
  if (tid < 16){
    b4L[tid]=b4p[tid]; eb1L[tid]=eb1p[tid];
    float acc=0.f;
    for (int j=0;j<16;j++) acc += a2e[j] * We2[j*16+tid];
    w16L[tid]=acc;
  }
  if (tid < 4) eb2L[tid] = eb2p[tid];
  __syncthreads();

  int i = blockIdx.x*256 + tid;
  if (i >= NE) return;
  int s = clampi(ei[i]);
  int d = clampi(ei[NE + i]);
  float f[40];
  {
    const float4* xs = (const float4*)(x1 + (size_t)s*16);
    float4 q0=xs[0], q1=xs[1], q2=xs[2], q3=xs[3];
    f[0]=q0.x; f[1]=q0.y; f[2]=q0.z; f[3]=q0.w;
    f[4]=q1.x; f[5]=q1.y; f[6]=q1.z; f[7]=q1.w;
    f[8]=q2.x; f[9]=q2.y; f[10]=q2.z; f[11]=q2.w;
    f[12]=q3.x; f[13]=q3.y; f[14]=q3.z; f[15]=q3.w;
    const float2* eap = (const float2*)ea + (size_t)i*3;
    float2 u0=eap[0], u1=eap[1], u2=eap[2];
    f[16]=u0.x; f[17]=u0.y; f[18]=u1.x;
    f[19]=u1.y; f[20]=u2.x; f[21]=u2.y;
    const float4* xd = (const float4*)(x1 + (size_t)d*16);
    float4 r0=xd[0], r1=xd[1], r2=xd[2], r3=xd[3];
    f[22]=r0.x; f[23]=r0.y; f[24]=r0.z; f[25]=r0.w;
    f[26]=r1.x; f[27]=r1.y; f[28]=r1.z; f[29]=r1.w;
    f[30]=r2.x; f[31]=r2.y; f[32]=r2.z; f[33]=r2.w;
    f[34]=r3.x; f[35]=r3.y; f[36]=r3.z; f[37]=r3.w;
    f[38]=0.f; f[39]=0.f;
  }
  float a1[32];
  #pragma unroll
  for (int j=0;j<32;j++) a1[j] = fmaxf(dotl<10>(f, &w1L[j*40]) + b1L[j], 0.f);
  float a2[64];
  #pragma unroll
  for (int j=0;j<64;j++) a2[j] = fmaxf(dotl<8>(a1, &w2L[j*32]) + b2L[j], 0.f);
  float a3[32];
  #pragma unroll
  for (int j=0;j<32;j++) a3[j] = fmaxf(dotl<16>(a2, &w3L[j*64]) + b3L[j], 0.f);
  float e[16];
  #pragma unroll
  for (int j=0;j<16;j++) e[j] = dotl<8>(a3, &w4L[j*32]) + b4L[j];

  // edge head + log_softmax(4)
  float t[16];
  #pragma unroll
  for (int j=0;j<16;j++) t[j] = fmaxf(dotl<4>(e, &ew1L[j*16]) + eb1L[j], 0.f);
  float y0 = fmaxf(dotl<4>(t, &ew2L[0])  + eb2L[0], 0.f);
  float y1 = fmaxf(dotl<4>(t, &ew2L[16]) + eb2L[1], 0.f);
  float y2 = fmaxf(dotl<4>(t, &ew2L[32]) + eb2L[2], 0.f);
  float y3 = fmaxf(dotl<4>(t, &ew2L[48]) + eb2L[3], 0.f);
  float m = fmaxf(fmaxf(y0,y1), fmaxf(y2,y3));
  float l = m + __logf(__expf(y0-m)+__expf(y1-m)+__expf(y2-m)+__expf(y3-m));
  float4 eo; eo.x = y0-l; eo.y = y1-l; eo.z = y2-l; eo.w = y3-l;
  ((float4*)eout)[i] = eo;

  // conv2 alpha -> CSR scatter
  float al = hs2[s] + hd2[d];
  #pragma unroll
  for (int k=0;k<16;k++) al += e[k]*w16L[k];
  al = al > 0.f ? al : 0.2f*al;
  float ex = __expf(al);
  int pos = off[d] + atomicAdd(&cnt[d], 1);
  edata[pos] = make_float2(ex, __int_as_float(s));
}

// ---------------- k7: x2 -> node head -> log_softmax(2) --------------------
__global__ __launch_bounds__(256,4) void k7(const float* __restrict__ accb,
    const float* __restrict__ sb, const float* __restrict__ c2b,
    const float* __restrict__ w1p, const float* __restrict__ b1p,
    const float* __restrict__ w2p, const float* __restrict__ b2p,
    float* __restrict__ nout)
{
  __shared__ float wL[256], bL[16], w2L[32], b2L[2], cb[16];
  int tid = threadIdx.x;
  wL[tid] = w1p[tid];
  if (tid < 16){ bL[tid]=b1p[tid]; cb[tid]=c2b[tid]; }
  if (tid < 32) w2L[tid] = w2p[tid];
  if (tid < 2)  b2L[tid] = b2p[tid];
  __syncthreads();
  int n = blockIdx.x*256 + tid;
  if (n >= NN) return;
  float inv = 1.f/(sb[n] + 1e-16f);
  const float* xp = accb + (size_t)n*16;
  float v[16];
  #pragma unroll
  for (int j=0;j<16;j++) v[j] = xp[j]*inv + cb[j];
  float t[16];
  #pragma unroll
  for (int j=0;j<16;j++){
    float acc = bL[j];
    #pragma unroll
    for (int k=0;k<16;k++) acc += v[k]*wL[j*16+k];
    t[j] = fmaxf(acc, 0.f);
  }
  float y0 = b2L[0], y1 = b2L[1];
  #pragma unroll
  for (int k=0;k<16;k++){ y0 += t[k]*w2L[k]; y1 += t[k]*w2L[16+k]; }
  y0 = fmaxf(y0, 0.f); y1 = fmaxf(y1, 0.f);
  float m = fmaxf(y0, y1);
  float l = m + __logf(__expf(y0-m) + __expf(y1-m));
  float2 no; no.x = y0-l; no.y = y1-l;
  ((float2*)nout)[n] = no;
}

extern "C" void kernel_launch(void* const* d_in, const int* in_sizes, int n_in,
                              void* d_out, int out_size, void* d_ws, size_t ws_size,
                              hipStream_t stream)
{
  const float* x  = (const float*)d_in[0];
  const int* ei   = (const int*)d_in[1];
  const float* ea = (const float*)d_in[2];
  const float* c1Wx = (const float*)d_in[3];
  const float* c1We = (const float*)d_in[4];
  const float* c1as = (const float*)d_in[5];
  const float* c1ad = (const float*)d_in[6];
  const float* c1ae = (const float*)d_in[7];
  const float* c1b  = (const float*)d_in[8];
  const float* e1w1 = (const float*)d_in[9];
  const float* e1b1 = (const float*)d_in[10];
  const float* e1w2 = (const float*)d_in[11];
  const float* e1b2 = (const float*)d_in[12];
  const float* e1w3 = (const float*)d_in[13];
  const float* e1b3 = (const float*)d_in[14];
  const float* e1w4 = (const float*)d_in[15];
  const float* e1b4 = (const float*)d_in[16];
  const float* c2Wx = (const float*)d_in[17];
  const float* c2We = (const float*)d_in[18];
  const float* c2as = (const float*)d_in[19];
  const float* c2ad = (const float*)d_in[20];
  const float* c2ae = (const float*)d_in[21];
  const float* c2b  = (const float*)d_in[22];
  const float* nlw1 = (const float*)d_in[23];
  const float* nlb1 = (const float*)d_in[24];
  const float* nlw2 = (const float*)d_in[25];
  const float* nlb2 = (const float*)d_in[26];
  const float* elw1 = (const float*)d_in[27];
  const float* elb1 = (const float*)d_in[28];
  const float* elw2 = (const float*)d_in[29];
  const float* elb2 = (const float*)d_in[30];

  float* ws = (float*)d_ws;
  const size_t N = NN;
  int* off   = (int*)ws;                 // N+1
  int* cnt   = (int*)ws + (N + 4);       // N
  float* h   = ws + 2*N + 8;             // 16N (h1, then h2)
  float* hs  = h  + 16*N;                // N  (hs1, then hs2)
  float* hd  = hs + N;                   // N
  float* x1  = hd + N;                   // 16N
  float* acc = x1 + 16*N;                // 16N
  float* s   = acc + 16*N;               // N
  float2* edata = (float2*)(s + N);      // NE float2 (offset 53N+8 floats, even -> 8B aligned)

  float* nout = (float*)d_out;            // [100000, 2]
  float* eout = (float*)d_out + 200000;   // [3200000, 4]

  const int GE = (NE + 255)/256;
  const int GN = (NN + 255)/256;

  hipMemsetAsync(cnt, 0, N*sizeof(int), stream);
  khist<<<GE, 256, 0, stream>>>(ei, cnt);
  kscan<<<1, 1024, 0, stream>>>(cnt, off);          // off = scan(cnt); cnt = 0
  k1<<<GN, 256, 0, stream>>>(x, c1Wx, c1as, c1ad, h, hs, hd);
  k2a<<<GE, 256, 0, stream>>>(ei, ea, c1We, c1ae, hs, hd, off, cnt, edata);
  kagg<<<(NN+15)/16, 256, 0, stream>>>(edata, off, h, acc, s, cnt);   // also re-zeros cnt
  k4<<<GN, 256, 0, stream>>>(acc, s, c1b, c2Wx, c2as, c2ad, x1, h, hs, hd);
  k5<<<GE, 256, 0, stream>>>(ei, ea, x1, hs, hd,
      e1w1, e1b1, e1w2, e1b2, e1w3, e1b3, e1w4, e1b4,
      c2We, c2ae, elw1, elb1, elw2, elb2,
      off, cnt, edata, eout);
  kagg<<<(NN+15)/16, 256, 0, stream>>>(edata, off, h, acc, s, cnt);
  k7<<<GN, 256, 0, stream>>>(acc, s, c2b, nlw1, nlb1, nlw2, nlb2, nout);
}